// Round 8
// baseline (393.637 us; speedup 1.0000x reference)
//
#include <hip/hip_runtime.h>
#include <hip/hip_bf16.h>
#include <math.h>

#define N_B   64
#define DIM   256
#define SEQ   1024
#define CF    0.32768f        // (1-2*eta)^5
#define CF2   0.1073741824f   // CF^2
#define BETA  0.59049f        // (1-eta)^5
#define EPSC  1e-10f
#define NSWEEP_Q 3
#define ROUNDS_Q (NSWEEP_Q*63)
#define ROUNDS_STEP 63

// ws layout in floats:
// [0]=decay [1]=trDD, [16..271]=bmean, Dt(256*64), DDT(64*64),
// Q(64*64), R0(64*64), U(64), M(1024*256)
#define OFF_BMEAN 16
#define OFF_DT    (OFF_BMEAN + DIM)          // Dt[k][b] = bubbles[b][k]-bmean[k]
#define OFF_DDT   (OFF_DT + DIM*N_B)
#define OFF_Q     (OFF_DDT + N_B*N_B)        // Q row-major [r][i]
#define OFF_R0    (OFF_Q + N_B*N_B)          // CF2 * (Q^T DD^T Q), full square
#define OFF_U     (OFF_R0 + N_B*N_B)         // u = Q^T 1
#define OFF_M     (OFF_U + 64)

__global__ __launch_bounds__(256) void prep_kernel(const float* __restrict__ bubbles,
                                                   const float* __restrict__ mdecay,
                                                   float* __restrict__ ws) {
    int d = threadIdx.x;
    float s = 0.f;
    for (int b = 0; b < N_B; ++b) s += bubbles[b*DIM + d];
    float bm = s * (1.f/64.f);
    ws[OFF_BMEAN + d] = bm;
    float sq = 0.f;
    for (int b = 0; b < N_B; ++b) {
        float v = bubbles[b*DIM + d] - bm;
        ws[OFF_DT + d*N_B + b] = v;          // transposed store
        sq += v*v;
    }
    __shared__ float red[256];
    red[d] = sq;
    __syncthreads();
    for (int o = 128; o > 0; o >>= 1) {
        if (d < o) red[d] += red[d+o];
        __syncthreads();
    }
    if (d == 0) {
        ws[1] = red[0];                               // ||D||_F^2 = tr(D D^T)
        ws[0] = 1.f/(1.f + expf(-mdecay[0]));         // sigmoid(memory_decay)
    }
}

// DDT[i][j] = sum_k Dt[k][i]*Dt[k][j]
__global__ __launch_bounds__(64) void ddt_kernel(float* __restrict__ ws) {
    const float* Dt = ws + OFF_DT;
    int i = blockIdx.x, j = threadIdx.x;
    __shared__ float coli[DIM];
    #pragma unroll
    for (int kk = 0; kk < 4; ++kk) coli[j + 64*kk] = Dt[(j + 64*kk)*N_B + i];
    __syncthreads();
    float acc = 0.f;
    #pragma unroll 8
    for (int k = 0; k < DIM; ++k) acc += coli[k] * Dt[k*N_B + j];
    ws[OFF_DDT + i*64 + j] = acc;
}

// upper-triangle storage address for symmetric A in a [64][65] buffer
__device__ __forceinline__ int triaddr(int i, int j) {
    int mn = min(i, j), mx = max(i, j);
    return mn*65 + mx;
}

// linear id L in [0,496) -> slot-pair (a<b), a,b in [0,32)
__device__ __forceinline__ void tri_decomp(int L, int& a, int& b) {
    int a_ = 0, S = 0;
    while (S + (31 - a_) <= L) { S += 31 - a_; ++a_; }
    a = a_; b = a_ + 1 + (L - S);
}

#define SLOT_INIT(k, p, q, f) { f = ((k) == 0); p = f ? 63 : (k); q = f ? 0 : (63 - (k)); }
#define SLOT_ADV(p, q, f)     { if (!(f)) p = (p == 62) ? 0 : p + 1; q = (q == 62) ? 0 : q + 1; }

// block 0: one-time eigendecomposition of DD^T (Jacobi + Q accumulation),
//          stores Q, R0 = CF2*Q^T DD^T Q (exact rotated matrix), u = Q^T 1.
// block 1: sequential scan producing M[t] (independent of block 0).
__global__ __launch_bounds__(256) void mid_kernel(const int* __restrict__ tokens,
                                                  const float* __restrict__ embed,
                                                  float* __restrict__ ws) {
    const int tid = threadIdx.x;
    if (blockIdx.x == 1) {
        // ---- scan ----
        int d = tid;
        float decay = ws[0];
        float bm = ws[OFF_BMEAN + d];
        const float omd = 1.f - decay;
        const float omb = 1.f - BETA;
        float mu = 0.f;
        for (int t0 = 0; t0 < SEQ; t0 += 16) {
            float x[16];
            #pragma unroll
            for (int u = 0; u < 16; ++u)
                x[u] = embed[tokens[t0+u]*DIM + d];
            #pragma unroll
            for (int u = 0; u < 16; ++u) {
                float xwm = x[u] + decay*mu;
                float m = BETA*bm + omb*xwm;
                ws[OFF_M + (t0+u)*DIM + d] = m;
                mu = decay*mu + omd*m;
            }
        }
        return;
    }

    // ---- eigQ ----
    __shared__ float A[64][65];
    __shared__ float Qm[64][65];
    __shared__ float2 cs[32];
    float* Ad = &A[0][0];

    {
        const float* DDT = ws + OFF_DDT;
        int i  = tid >> 2;
        int jb = (tid & 3) * 16;
        #pragma unroll
        for (int jj = 0; jj < 16; ++jj) {
            int j = jb + jj;
            A[i][j]  = DDT[i*64 + j];
            Qm[i][j] = (i == j) ? 1.f : 0.f;
        }
    }
    __syncthreads();

    const bool active = (tid < 248);
    int kr0 = 0, kc0 = 1, kr1 = 0, kc1 = 1;
    if (active) { tri_decomp(2*tid, kr0, kc0); tri_decomp(2*tid+1, kr1, kc1); }
    int pr0, qr0, pc0, qc0, pr1, qr1, pc1, qc1;
    bool fr0, fc0, fr1, fc1;
    SLOT_INIT(kr0, pr0, qr0, fr0);
    SLOT_INIT(kc0, pc0, qc0, fc0);
    SLOT_INIT(kr1, pr1, qr1, fr1);
    SLOT_INIT(kc1, pc1, qc1, fc1);
    int pA = 63, qA = 0; bool fA;
    if (tid < 32) SLOT_INIT(tid, pA, qA, fA);
    const int kq = tid & 31;
    const int qg = (tid >> 5) * 8;
    int pQ, qQ; bool fQ;
    SLOT_INIT(kq, pQ, qQ, fQ);

    for (int rr = 0; rr < ROUNDS_Q; ++rr) {
        if (tid < 32) {
            int aqp = triaddr(pA, qA);
            float app = Ad[pA*65 + pA];
            float aqq = Ad[qA*65 + qA];
            float apq = Ad[aqp];
            float ccf = 1.f, ssf = 0.f, ttf = 0.f;
            if (fabsf(apq) > 1e-36f) {
                float tau = (aqq - app)/(2.f*apq);
                ttf = 1.f/(fabsf(tau) + sqrtf(1.f + tau*tau));
                if (tau < 0.f) ttf = -ttf;
                ccf = rsqrtf(1.f + ttf*ttf);
                ssf = ttf*ccf;
            }
            cs[tid] = make_float2(ccf, ssf);
            Ad[pA*65 + pA] = app - ttf*apq;
            Ad[qA*65 + qA] = aqq + ttf*apq;
            Ad[aqp] = 0.f;
        }
        __syncthreads();

        if (active) {
            {
                float2 cr = cs[kr0], cc2 = cs[kc0];
                int a00 = triaddr(pr0, pc0), a01 = triaddr(pr0, qc0);
                int a10 = triaddr(qr0, pc0), a11 = triaddr(qr0, qc0);
                float x00 = Ad[a00], x01 = Ad[a01], x10 = Ad[a10], x11 = Ad[a11];
                float t0x = cc2.x*x00 - cc2.y*x01, t0y = cc2.y*x00 + cc2.x*x01;
                float t1x = cc2.x*x10 - cc2.y*x11, t1y = cc2.y*x10 + cc2.x*x11;
                Ad[a00] = cr.x*t0x - cr.y*t1x;
                Ad[a01] = cr.x*t0y - cr.y*t1y;
                Ad[a10] = cr.y*t0x + cr.x*t1x;
                Ad[a11] = cr.y*t0y + cr.x*t1y;
            }
            {
                float2 cr = cs[kr1], cc2 = cs[kc1];
                int a00 = triaddr(pr1, pc1), a01 = triaddr(pr1, qc1);
                int a10 = triaddr(qr1, pc1), a11 = triaddr(qr1, qc1);
                float x00 = Ad[a00], x01 = Ad[a01], x10 = Ad[a10], x11 = Ad[a11];
                float t0x = cc2.x*x00 - cc2.y*x01, t0y = cc2.y*x00 + cc2.x*x01;
                float t1x = cc2.x*x10 - cc2.y*x11, t1y = cc2.y*x10 + cc2.x*x11;
                Ad[a00] = cr.x*t0x - cr.y*t1x;
                Ad[a01] = cr.x*t0y - cr.y*t1y;
                Ad[a10] = cr.y*t0x + cr.x*t1x;
                Ad[a11] = cr.y*t0y + cr.x*t1y;
            }
        }
        // Q <- Q * J (column rotation), all 256 threads: pair kq, rows qg..qg+7
        {
            float2 cq = cs[kq];
            #pragma unroll
            for (int j = 0; j < 8; ++j) {
                int r = qg + j;
                float x = Qm[r][pQ], z = Qm[r][qQ];
                Qm[r][pQ] = cq.x*x - cq.y*z;
                Qm[r][qQ] = cq.y*x + cq.x*z;
            }
        }

        SLOT_ADV(pr0, qr0, fr0);
        SLOT_ADV(pc0, qc0, fc0);
        SLOT_ADV(pr1, qr1, fr1);
        SLOT_ADV(pc1, qc1, fc1);
        if (tid < 32) SLOT_ADV(pA, qA, fA);
        SLOT_ADV(pQ, qQ, fQ);
        __syncthreads();
    }

    // store R0 (scaled, full square from upper triangle), Q, u
    {
        int i  = tid >> 2;
        int jb = (tid & 3) * 16;
        #pragma unroll
        for (int jj = 0; jj < 16; ++jj) {
            int j = jb + jj;
            ws[OFF_R0 + i*64 + j] = CF2 * Ad[triaddr(i, j)];
            ws[OFF_Q  + i*64 + j] = Qm[i][j];          // row-major [r][i]
        }
    }
    if (tid < 64) {
        float acc = 0.f;
        #pragma unroll 8
        for (int r = 0; r < 64; ++r) acc += Qm[r][tid];
        ws[OFF_U + tid] = acc;
    }
}

__global__ __launch_bounds__(256) void step_kernel(const float* __restrict__ ws,
                                                   float* __restrict__ out) {
    const int t    = blockIdx.x;
    const int tid  = threadIdx.x;
    const int lane = tid & 63;
    const int w    = tid >> 6;

    __shared__ float A[64][65];     // symmetric: only i<=j locations authoritative
    __shared__ float yv[64];
    __shared__ float wv[64];
    __shared__ float uL[64];
    __shared__ float ml[DIM];
    __shared__ float2 cs[32];
    __shared__ float ypart[4][64];
    __shared__ float wpart[4];
    __shared__ float sorted[64];

    float* Ad = &A[0][0];
    const float* Dt = ws + OFF_DT;
    const float* m  = ws + OFF_M + (size_t)t*DIM;

    // load m, compute |m|^2 (block reduce)
    float mv = m[tid];
    ml[tid] = mv;
    float pp = mv*mv;
    #pragma unroll
    for (int o = 1; o < 64; o <<= 1) pp += __shfl_xor(pp, o);
    if (lane == 0) wpart[w] = pp;
    __syncthreads();
    const float mm2 = wpart[0]+wpart[1]+wpart[2]+wpart[3];

    // y = D m : wave w handles k-chunk [64w, 64w+64), coalesced Dt reads
    {
        float acc = 0.f;
        const float* DtB = Dt + (w*64)*N_B + lane;
        #pragma unroll 8
        for (int kk = 0; kk < 64; ++kk) acc += DtB[kk*N_B] * ml[w*64 + kk];
        ypart[w][lane] = acc;
    }
    __syncthreads();
    if (tid < 64) yv[tid] = ypart[0][tid]+ypart[1][tid]+ypart[2][tid]+ypart[3][tid];
    __syncthreads();

    // w = Q^T y : wave w sums j-chunk [16w,16w+16); coalesced Q reads
    {
        float acc = 0.f;
        const float* Qg = ws + OFF_Q + (w*16)*64 + lane;
        #pragma unroll
        for (int jj = 0; jj < 16; ++jj) acc += Qg[jj*64] * yv[w*16 + jj];
        ypart[w][lane] = acc;
    }
    if (tid >= 64 && tid < 128) uL[tid-64] = ws[OFF_U + tid-64];
    __syncthreads();
    if (tid < 64) wv[tid] = ypart[0][tid]+ypart[1][tid]+ypart[2][tid]+ypart[3][tid];
    __syncthreads();

    const float trDD = ws[1];
    const float tr   = mm2 + (CF2/64.f)*trDD;          // trace(rho)
    const float inv  = 1.f/(64.f*tr);

    // build A' = (R0 + mm2*u u^T + CF*(u w^T + w u^T)) * inv  — exact similarity of A_t
    {
        int i  = tid >> 2;
        int jb = (tid & 3) * 16;
        const float4* r4p = (const float4*)(ws + OFF_R0 + i*64 + jb);
        float ui = uL[i], wi = wv[i];
        #pragma unroll
        for (int u4 = 0; u4 < 4; ++u4) {
            float4 r4 = r4p[u4];
            int j = jb + u4*4;
            A[i][j+0] = (r4.x + mm2*ui*uL[j+0] + CF*(ui*wv[j+0] + wi*uL[j+0])) * inv;
            A[i][j+1] = (r4.y + mm2*ui*uL[j+1] + CF*(ui*wv[j+1] + wi*uL[j+1])) * inv;
            A[i][j+2] = (r4.z + mm2*ui*uL[j+2] + CF*(ui*wv[j+2] + wi*uL[j+2])) * inv;
            A[i][j+3] = (r4.w + mm2*ui*uL[j+3] + CF*(ui*wv[j+3] + wi*uL[j+3])) * inv;
        }
    }
    __syncthreads();

    // one warm-start sweep of symmetric cyclic Jacobi on the upper triangle
    const bool active = (tid < 248);
    int kr0 = 0, kc0 = 1, kr1 = 0, kc1 = 1;
    if (active) { tri_decomp(2*tid, kr0, kc0); tri_decomp(2*tid+1, kr1, kc1); }
    int pr0, qr0, pc0, qc0, pr1, qr1, pc1, qc1;
    bool fr0, fc0, fr1, fc1;
    SLOT_INIT(kr0, pr0, qr0, fr0);
    SLOT_INIT(kc0, pc0, qc0, fc0);
    SLOT_INIT(kr1, pr1, qr1, fr1);
    SLOT_INIT(kc1, pc1, qc1, fc1);
    int pA = 63, qA = 0; bool fA;
    if (tid < 32) SLOT_INIT(tid, pA, qA, fA);

    for (int rr = 0; rr < ROUNDS_STEP; ++rr) {
        if (tid < 32) {
            int aqp = triaddr(pA, qA);
            float app = Ad[pA*65 + pA];
            float aqq = Ad[qA*65 + qA];
            float apq = Ad[aqp];
            float ccf = 1.f, ssf = 0.f, ttf = 0.f;
            if (fabsf(apq) > 1e-36f) {
                float tau = (aqq - app)/(2.f*apq);
                ttf = 1.f/(fabsf(tau) + sqrtf(1.f + tau*tau));
                if (tau < 0.f) ttf = -ttf;
                ccf = rsqrtf(1.f + ttf*ttf);
                ssf = ttf*ccf;
            }
            cs[tid] = make_float2(ccf, ssf);
            Ad[pA*65 + pA] = app - ttf*apq;
            Ad[qA*65 + qA] = aqq + ttf*apq;
            Ad[aqp] = 0.f;
        }
        __syncthreads();

        if (active) {
            {
                float2 cr = cs[kr0], cc2 = cs[kc0];
                int a00 = triaddr(pr0, pc0), a01 = triaddr(pr0, qc0);
                int a10 = triaddr(qr0, pc0), a11 = triaddr(qr0, qc0);
                float x00 = Ad[a00], x01 = Ad[a01], x10 = Ad[a10], x11 = Ad[a11];
                float t0x = cc2.x*x00 - cc2.y*x01, t0y = cc2.y*x00 + cc2.x*x01;
                float t1x = cc2.x*x10 - cc2.y*x11, t1y = cc2.y*x10 + cc2.x*x11;
                Ad[a00] = cr.x*t0x - cr.y*t1x;
                Ad[a01] = cr.x*t0y - cr.y*t1y;
                Ad[a10] = cr.y*t0x + cr.x*t1x;
                Ad[a11] = cr.y*t0y + cr.x*t1y;
            }
            {
                float2 cr = cs[kr1], cc2 = cs[kc1];
                int a00 = triaddr(pr1, pc1), a01 = triaddr(pr1, qc1);
                int a10 = triaddr(qr1, pc1), a11 = triaddr(qr1, qc1);
                float x00 = Ad[a00], x01 = Ad[a01], x10 = Ad[a10], x11 = Ad[a11];
                float t0x = cc2.x*x00 - cc2.y*x01, t0y = cc2.y*x00 + cc2.x*x01;
                float t1x = cc2.x*x10 - cc2.y*x11, t1y = cc2.y*x10 + cc2.x*x11;
                Ad[a00] = cr.x*t0x - cr.y*t1x;
                Ad[a01] = cr.x*t0y - cr.y*t1y;
                Ad[a10] = cr.y*t0x + cr.x*t1x;
                Ad[a11] = cr.y*t0y + cr.x*t1y;
            }
        }

        SLOT_ADV(pr0, qr0, fr0);
        SLOT_ADV(pc0, qc0, fc0);
        SLOT_ADV(pr1, qr1, fr1);
        SLOT_ADV(pc1, qc1, fc1);
        if (tid < 32) SLOT_ADV(pA, qA, fA);
        __syncthreads();
    }

    // eigenvalues = diagonal; bitonic sort ascending across wave 0
    if (tid < 64) {
        float v = A[tid][tid];
        #pragma unroll
        for (int k = 2; k <= 64; k <<= 1) {
            #pragma unroll
            for (int j = k >> 1; j > 0; j >>= 1) {
                float other = __shfl_xor(v, j);
                bool up    = ((tid & k) == 0);
                bool lower = ((tid & j) == 0);
                v = (lower == up) ? fminf(v, other) : fmaxf(v, other);
            }
        }
        sorted[tid] = v;
    }
    __syncthreads();

    const float invS = 1.f/(1.f + 192.f*EPSC);
    out[(size_t)t*DIM + tid] = (tid < 192) ? EPSC*invS
                                           : fmaxf(sorted[tid-192], EPSC)*invS;
}

extern "C" void kernel_launch(void* const* d_in, const int* in_sizes, int n_in,
                              void* d_out, int out_size, void* d_ws, size_t ws_size,
                              hipStream_t stream) {
    const int*   tokens  = (const int*)d_in[0];
    const float* embed   = (const float*)d_in[1];
    const float* bubbles = (const float*)d_in[2];
    const float* mdecay  = (const float*)d_in[3];
    float* out = (float*)d_out;
    float* ws  = (float*)d_ws;

    hipLaunchKernelGGL(prep_kernel, dim3(1),    dim3(256), 0, stream, bubbles, mdecay, ws);
    hipLaunchKernelGGL(ddt_kernel,  dim3(64),   dim3(64),  0, stream, ws);
    hipLaunchKernelGGL(mid_kernel,  dim3(2),    dim3(256), 0, stream, tokens, embed, ws);
    hipLaunchKernelGGL(step_kernel, dim3(1024), dim3(256), 0, stream, ws, out);
}